// Round 14
// baseline (333.759 us; speedup 1.0000x reference)
//
#include <hip/hip_runtime.h>

typedef unsigned short ushort_t;
typedef unsigned int uint_t;

constexpr int Bb = 2, Tt = 12, Nn = 50000, Hh = 16, Ee = 800000;
constexpr int T1 = 10, T2 = 8;
constexpr int F = 320;     // features per node, layout f = t*32 + b*16 + h
constexpr int NP = 50176;  // padded node stride for per-XCD deg copies
constexpr int CAP = 64;    // bucket capacity per dst

#define DEV __device__ __forceinline__

DEV float bf2f(ushort_t u) { return __uint_as_float(((uint_t)u) << 16); }
DEV ushort_t f2bf(float f) {
  uint_t u = __float_as_uint(f);
  u += 0x7fffu + ((u >> 16) & 1u);  // RNE
  return (ushort_t)(u >> 16);
}
DEV float blo(uint_t u) { return __uint_as_float(u << 16); }
DEV float bhi(uint_t u) { return __uint_as_float(u & 0xffff0000u); }
DEV float sigm(float x) { return 1.0f / (1.0f + __expf(-x)); }

// Flag-aware loads: flags[0]=1 -> floats stored as bf16; flags[1]=1 -> ints are int64.
DEV float loadF(const void* p, int j, int isb) {
  return isb ? bf2f(((const ushort_t*)p)[j]) : ((const float*)p)[j];
}
DEV int loadI(const void* p, long long j, int is64) {
  return is64 ? (int)(((const long long*)p)[j]) : ((const int*)p)[j];
}

// ---------------------------------------------------------------------------
// Weight prep + dtype detection + workspace zeroing (one dispatch).
// ---------------------------------------------------------------------------
__global__ void k_wprep(const void* ew, const void* ei,
                        const void* t1Pw, const void* t1Pb,
                        const void* t1Qw, const void* t1Qb,
                        const void* t1Rw, const void* t1Rb,
                        const void* t2Pw, const void* t2Pb,
                        const void* t2Qw, const void* t2Qb,
                        const void* t2Rw, const void* t2Rb,
                        const void* chw, const void* chb,
                        const void* lw, const void* lb,
                        int* flags, float* W, uint_t* zero_base) {
  int gid = blockIdx.x * 256 + threadIdx.x;
  if (gid < 9 * NP) zero_base[gid] = 0u;
  if (blockIdx.x != 0) return;

  __shared__ int sflags[2];
  int tid = threadIdx.x;
  if (tid < 64) {
    int lane = tid;
    const ushort_t* u = (const ushort_t*)ew;
    int cnt = 0;
    for (int j = lane; j < 512; j += 64) cnt += (u[j] < 0x3F80u) ? 1 : 0;
#pragma unroll
    for (int d = 32; d; d >>= 1) cnt += __shfl_xor(cnt, d, 64);
    const int* e32 = (const int*)ei;
    int even_nz = 0, odd_nz = 0;
    for (int j = 2 * lane; j < 256; j += 128) {
      even_nz |= (e32[j] != 0);
      odd_nz |= (e32[j + 1] != 0);
    }
    unsigned long long be = __ballot(even_nz), bo = __ballot(odd_nz);
    if (lane == 0) {
      int f0 = (cnt >= 450) ? 1 : 0;
      int f1 = (bo == 0ull && be != 0ull) ? 1 : 0;
      sflags[0] = f0; sflags[1] = f1;
      flags[0] = f0; flags[1] = f1;
    }
  }
  __syncthreads();
  int isb = sflags[0];
#define CVT(src, off, n) for (int j = tid; j < (n); j += 256) W[(off) + j] = loadF(src, j, isb);
  CVT(t1Pw, 0, 48)   CVT(t1Pb, 48, 16)
  CVT(t1Qw, 64, 48)  CVT(t1Qb, 112, 16)
  CVT(t1Rw, 128, 48) CVT(t1Rb, 176, 16)
  CVT(t2Pw, 192, 768)  CVT(t2Pb, 960, 16)
  CVT(t2Qw, 976, 768)  CVT(t2Qb, 1744, 16)
  CVT(t2Rw, 1760, 768) CVT(t2Rb, 2528, 16)
  CVT(chw, 2544, 512)  CVT(chb, 3056, 16)
  CVT(lw, 3072, 32)    CVT(lb, 3104, 2)
#undef CVT
}

// ---------------------------------------------------------------------------
// Fused tc1 + degree accumulation + bucket scatter (single edge pass).
// Block = 320 threads = 16 nodes x 20 (b,t) slots; one GLU per thread (max
// TLP), output staged in skewed LDS then written as 16 FULL 640 B rows,
// fully coalesced (fixes the 32 B partial-line store of earlier rounds).
// Buckets store packed (src<<16 | bf16(w)) — 4 B entries halve scatter-line
// traffic; dis[s] applied at gather, dis[d] in the k_agg epilogue.
// deg8: 8 XCD-local copies (blockIdx&7). Grid 3125 x 320 = 1M >= Ee.
// ---------------------------------------------------------------------------
__global__ __launch_bounds__(320) void k_pre(const void* __restrict__ x,
                                             const void* __restrict__ ei,
                                             const void* __restrict__ ew,
                                             const float* __restrict__ W,
                                             const int* __restrict__ flags,
                                             uint_t* __restrict__ xfh,
                                             float* __restrict__ deg8,
                                             int* __restrict__ cnt,
                                             uint_t* __restrict__ ecv) {
  __shared__ uint_t sx[16 * 161];  // node stride 161 dwords (skew: 2-way max)
  int tid = threadIdx.x;
  int id = blockIdx.x * 320 + tid;
  int isb = flags[0];
  if (id < Ee) {
    int is64 = flags[1];
    int s = loadI(ei, id, is64), d = loadI(ei, (long long)Ee + id, is64);
    float w = loadF(ew, id, isb);
    atomicAdd(&deg8[(blockIdx.x & 7) * NP + s], w);
    int pos = atomicAdd(&cnt[d], 1);
    if (pos < CAP) ecv[d * CAP + pos] = ((uint_t)s << 16) | (uint_t)f2bf(w);
  }
  {
    int nlocal = tid & 15, slot = tid >> 4;  // slot = b*10 + t, 0..19
    int t = slot % 10, b = slot / 10;
    int n = blockIdx.x * 16 + nlocal;
    float x0 = loadF(x, (b * Tt + t + 0) * Nn + n, isb);
    float x1 = loadF(x, (b * Tt + t + 1) * Nn + n, isb);
    float x2 = loadF(x, (b * Tt + t + 2) * Nn + n, isb);
    ushort_t g[16];
#pragma unroll
    for (int h = 0; h < 16; ++h) {
      float p = W[48 + h] + x0 * W[0 + h] + x1 * W[16 + h] + x2 * W[32 + h];
      float q = W[112 + h] + x0 * W[64 + h] + x1 * W[80 + h] + x2 * W[96 + h];
      float r = W[176 + h] + x0 * W[128 + h] + x1 * W[144 + h] + x2 * W[160 + h];
      g[h] = f2bf(fmaxf(fmaf(p, sigm(q), r), 0.0f));
    }
    // Stage: row nlocal, dwords slot*8 .. slot*8+7  (f = t*32 + b*16 + h).
    uint_t* row = sx + nlocal * 161 + (t * 16 + b * 8);  // dword offset = f/2
#pragma unroll
    for (int j = 0; j < 8; ++j) row[j] = (uint_t)g[2 * j] | ((uint_t)g[2 * j + 1] << 16);
  }
  __syncthreads();
  // Write 16 complete rows (2560 dwords) coalesced as 640 uint4.
  uint4* outp = (uint4*)(xfh + (size_t)blockIdx.x * 16 * (F / 2));
#pragma unroll
  for (int it = 0; it < 2; ++it) {
    int i = it * 320 + tid;       // 0..639
    int f = i * 4;                // dword index; 160 % 4 == 0 -> never crosses rows
    int nr = f / 160, of = f % 160;
    const uint_t* s = sx + nr * 161 + of;
    outp[i] = make_uint4(s[0], s[1], s[2], s[3]);
  }
}

// ---------------------------------------------------------------------------
// Reduce the 8 degree copies -> dis = 1/sqrt(deg), in place into copy 0.
// ---------------------------------------------------------------------------
__global__ __launch_bounds__(256) void k_dis(float* __restrict__ deg8) {
  int i = blockIdx.x * 256 + threadIdx.x;
  if (i >= Nn) return;
  float v = 0.0f;
#pragma unroll
  for (int j = 0; j < 8; ++j) v += deg8[j * NP + i];
  deg8[i] = (v > 0.0f) ? (1.0f / sqrtf(fmaxf(v, 1e-12f))) : 0.0f;
}

// ---------------------------------------------------------------------------
// Fused SpMM gather + Cheb combine + relu.  One wave per dst node.
// Packed 4 B bucket entries; valv = bf16(w) * dis[src]; 4-edge unroll
// (R10/R13-proven). Epilogue scales by -dis[dst], cheb-combines via
// wave-private LDS, stores h2 bf16.
// ---------------------------------------------------------------------------
__global__ __launch_bounds__(256) void k_agg(const int* __restrict__ cnt,
                                             const uint_t* __restrict__ ecv,
                                             const float* __restrict__ dis,
                                             const uint2* __restrict__ xf2,
                                             const float* __restrict__ W,
                                             ushort_t* __restrict__ h2) {
  __shared__ float sh[4][640];  // per wave: [0..319]=agg, [320..639]=x
  int wid = threadIdx.x >> 6;
  int lane = threadIdx.x & 63;
  int gw = blockIdx.x * 4 + wid;
  int deg = min(cnt[gw], CAP);
  int l16 = 64 + (lane & 15);
  float a0 = 0.f, a1 = 0.f, a2 = 0.f, a3 = 0.f;
  float c0 = 0.f, c1 = 0.f, c2 = 0.f, c3 = 0.f;

#define ACC(v, p, q)                                                          \
  a0 = fmaf(v, blo(p.x), a0); a1 = fmaf(v, bhi(p.x), a1);                     \
  a2 = fmaf(v, blo(p.y), a2); a3 = fmaf(v, bhi(p.y), a3);                     \
  c0 = fmaf(v, blo(q.x), c0); c1 = fmaf(v, bhi(q.x), c1);                     \
  c2 = fmaf(v, blo(q.y), c2); c3 = fmaf(v, bhi(q.y), c3);

  int colv = 0; float valv = 0.0f;
  if (lane < deg) {
    uint_t t = ecv[gw * CAP + lane];
    int src = t >> 16;
    colv = src * 80;  // row offset in uint2 units
    valv = bf2f((ushort_t)(t & 0xffffu)) * dis[src];
  }
  int e = 0;
  for (; e + 4 <= deg; e += 4) {
    int r0 = __shfl(colv, e + 0), r1 = __shfl(colv, e + 1);
    int r2 = __shfl(colv, e + 2), r3 = __shfl(colv, e + 3);
    float v0 = __shfl(valv, e + 0), v1 = __shfl(valv, e + 1);
    float v2 = __shfl(valv, e + 2), v3 = __shfl(valv, e + 3);
    uint2 p0 = xf2[r0 + lane], q0 = xf2[r0 + l16];
    uint2 p1 = xf2[r1 + lane], q1 = xf2[r1 + l16];
    uint2 p2 = xf2[r2 + lane], q2 = xf2[r2 + l16];
    uint2 p3 = xf2[r3 + lane], q3 = xf2[r3 + l16];
    ACC(v0, p0, q0) ACC(v1, p1, q1) ACC(v2, p2, q2) ACC(v3, p3, q3)
  }
  for (; e < deg; ++e) {
    int r = __shfl(colv, e);
    float v = __shfl(valv, e);
    uint2 p = xf2[r + lane], q = xf2[r + l16];
    ACC(v, p, q)
  }
#undef ACC

  float nd = -dis[gw];  // wave-uniform
  float* sa = sh[wid];
  float* sx = sh[wid] + 320;
  const uint2* xrow = xf2 + (size_t)gw * 80;
  uint2 xp = xrow[lane], xq = xrow[l16];
  ((float4*)sa)[lane] = make_float4(a0 * nd, a1 * nd, a2 * nd, a3 * nd);
  ((float4*)sx)[lane] = make_float4(blo(xp.x), bhi(xp.x), blo(xp.y), bhi(xp.y));
  if (lane < 16) {
    ((float4*)sa)[64 + lane] = make_float4(c0 * nd, c1 * nd, c2 * nd, c3 * nd);
    ((float4*)sx)[64 + lane] = make_float4(blo(xq.x), bhi(xq.x), blo(xq.y), bhi(xq.y));
  }
  __builtin_amdgcn_wave_barrier();  // wave-private LDS: block compiler reordering only
  int h = lane & 15;
  float w0[16], w1[16];
#pragma unroll
  for (int c = 0; c < 16; ++c) {
    w0[c] = W[2544 + c * 16 + h];
    w1[c] = W[2800 + c * 16 + h];
  }
  float bias = W[3056 + h];
  ushort_t* orow = h2 + (size_t)gw * F;
#pragma unroll
  for (int j = 0; j < 5; ++j) {
    int base2 = (lane & 48) + 64 * j;
    float o2 = bias;
#pragma unroll
    for (int c = 0; c < 16; ++c)
      o2 = fmaf(sx[base2 + c], w0[c], fmaf(sa[base2 + c], w1[c], o2));
    orow[lane + 64 * j] = f2bf(fmaxf(o2, 0.0f));
  }
}

// ---------------------------------------------------------------------------
// Fused tc2 GLU + mean + linear head.  Block = 16 nodes x 16 (b,t2) pairs.
// ---------------------------------------------------------------------------
__global__ __launch_bounds__(256) void k_tc2h(const ushort_t* __restrict__ h2,
                                              const float* __restrict__ W,
                                              float* __restrict__ out) {
  __shared__ float shh[16 * 330];  // node stride 330; f_lds = t*33 + b*16 + c
  __shared__ float sg[16 * 257];   // node stride 257; [pair*16 + h]
  int tid = threadIdx.x;
  int nb = blockIdx.x * 16;

  for (int i = tid; i < 16 * 40; i += 256) {
    int node = i / 40, j = i % 40;  // j-th uint4 covers f = 8j..8j+7
    uint4 q = ((const uint4*)(h2 + (size_t)(nb + node) * F))[j];
    int t = j >> 2;
    float* dstp = shh + node * 330 + t * 33 + (j & 3) * 8;
    dstp[0] = blo(q.x); dstp[1] = bhi(q.x);
    dstp[2] = blo(q.y); dstp[3] = bhi(q.y);
    dstp[4] = blo(q.z); dstp[5] = bhi(q.z);
    dstp[6] = blo(q.w); dstp[7] = bhi(q.w);
  }
  __syncthreads();

  {
    int node = tid >> 4, pair = tid & 15;
    int b = pair >> 3, t2 = pair & 7;
    const float* base = shh + node * 330 + b * 16;
    float hv[48];
#pragma unroll
    for (int k = 0; k < 3; ++k) {
      const float4* p = (const float4*)(base + (t2 + k) * 33);
      float4 e0 = p[0], e1 = p[1], e2 = p[2], e3 = p[3];
      hv[k * 16 + 0] = e0.x;  hv[k * 16 + 1] = e0.y;
      hv[k * 16 + 2] = e0.z;  hv[k * 16 + 3] = e0.w;
      hv[k * 16 + 4] = e1.x;  hv[k * 16 + 5] = e1.y;
      hv[k * 16 + 6] = e1.z;  hv[k * 16 + 7] = e1.w;
      hv[k * 16 + 8] = e2.x;  hv[k * 16 + 9] = e2.y;
      hv[k * 16 + 10] = e2.z; hv[k * 16 + 11] = e2.w;
      hv[k * 16 + 12] = e3.x; hv[k * 16 + 13] = e3.y;
      hv[k * 16 + 14] = e3.z; hv[k * 16 + 15] = e3.w;
    }
    float P[16], Q[16], R[16];
#pragma unroll
    for (int h = 0; h < 16; ++h) {
      P[h] = W[960 + h];
      Q[h] = W[1744 + h];
      R[h] = W[2528 + h];
    }
#pragma unroll
    for (int k = 0; k < 3; ++k) {
#pragma unroll
      for (int c = 0; c < 16; ++c) {
        float v = hv[k * 16 + c];
        const int wbase = k * 256 + c * 16;
#pragma unroll
        for (int h = 0; h < 16; ++h) {
          P[h] = fmaf(v, W[192 + wbase + h], P[h]);
          Q[h] = fmaf(v, W[976 + wbase + h], Q[h]);
          R[h] = fmaf(v, W[1760 + wbase + h], R[h]);
        }
      }
    }
    float* go = sg + node * 257 + pair * 16;
#pragma unroll
    for (int h = 0; h < 16; ++h)
      go[h] = fmaxf(fmaf(P[h], sigm(Q[h]), R[h]), 0.0f);
  }
  __syncthreads();

  if (tid < 32) {
    int node = tid >> 1, b = tid & 1;
    const float* gp = sg + node * 257 + b * 128;
    float mean[16];
#pragma unroll
    for (int h = 0; h < 16; ++h) mean[h] = 0.0f;
#pragma unroll
    for (int t2 = 0; t2 < T2; ++t2)
#pragma unroll
      for (int h = 0; h < 16; ++h) mean[h] += gp[t2 * 16 + h];
    float o0 = W[3104], o1 = W[3105];
#pragma unroll
    for (int h = 0; h < 16; ++h) {
      float m = mean[h] * 0.125f;
      o0 = fmaf(m, W[3072 + 2 * h], o0);
      o1 = fmaf(m, W[3072 + 2 * h + 1], o1);
    }
    ((float2*)out)[(size_t)b * Nn + nb + node] = make_float2(o0, o1);
  }
}

// ---------------------------------------------------------------------------
extern "C" void kernel_launch(void* const* d_in, const int* in_sizes, int n_in,
                              void* d_out, int out_size, void* d_ws, size_t ws_size,
                              hipStream_t stream) {
  (void)in_sizes; (void)n_in; (void)out_size; (void)ws_size;
  const void* x = d_in[0];
  const void* ei = d_in[1];
  const void* ew = d_in[2];

  char* wsb = (char*)d_ws;
  size_t off = 0;
  auto alloc = [&](size_t bytes) -> void* {
    void* p = wsb + off;
    off = (off + bytes + 255) & ~(size_t)255;
    return p;
  };
  int* flags = (int*)alloc(256);
  float* W = (float*)alloc(4096 * 4);
  float* deg8 = (float*)alloc((size_t)8 * NP * 4);       // copy0 becomes dis
  int* cnt = (int*)alloc((size_t)NP * 4);                // contiguous after deg8
  uint_t* ecv = (uint_t*)alloc((size_t)Nn * CAP * 4);    // packed (src<<16|bf16 w)
  ushort_t* xfh = (ushort_t*)alloc((size_t)Nn * F * 2);  // h1 bf16 (f = t*32+b*16+h)
  ushort_t* h2 = (ushort_t*)alloc((size_t)Nn * F * 2);   // cheb output bf16
  // total ~79 MB of d_ws

  int zblk = (9 * NP + 255) / 256;  // block 0 also does detection + weights
  k_wprep<<<zblk, 256, 0, stream>>>(
      ew, ei,
      d_in[3], d_in[4], d_in[5], d_in[6], d_in[7], d_in[8],
      d_in[9], d_in[10], d_in[11], d_in[12], d_in[13], d_in[14],
      d_in[15], d_in[16], d_in[17], d_in[18], flags, W, (uint_t*)deg8);

  k_pre<<<Nn / 16, 320, 0, stream>>>(x, ei, ew, W, flags, (uint_t*)xfh, deg8, cnt, ecv);
  k_dis<<<(Nn + 255) / 256, 256, 0, stream>>>(deg8);
  k_agg<<<Nn / 4, 256, 0, stream>>>(cnt, ecv, deg8, (const uint2*)xfh, W, h2);
  k_tc2h<<<Nn / 16, 256, 0, stream>>>(h2, W, (float*)d_out);
}

// Round 15
// 283.877 us; speedup vs baseline: 1.1757x; 1.1757x over previous
//
#include <hip/hip_runtime.h>

typedef unsigned short ushort_t;
typedef unsigned int uint_t;
typedef __attribute__((ext_vector_type(8))) short short8;
typedef __attribute__((ext_vector_type(4))) float float4v;

constexpr int Bb = 2, Tt = 12, Nn = 50000, Hh = 16, Ee = 800000;
constexpr int T1 = 10, T2 = 8;
constexpr int F = 320;     // features per node, layout f = t*32 + b*16 + h
constexpr int NP = 50176;  // padded node stride for per-XCD deg copies
constexpr int CAP = 64;    // bucket capacity per dst

#define DEV __device__ __forceinline__

DEV float bf2f(ushort_t u) { return __uint_as_float(((uint_t)u) << 16); }
DEV ushort_t f2bf(float f) {
  uint_t u = __float_as_uint(f);
  u += 0x7fffu + ((u >> 16) & 1u);  // RNE
  return (ushort_t)(u >> 16);
}
DEV float blo(uint_t u) { return __uint_as_float(u << 16); }
DEV float bhi(uint_t u) { return __uint_as_float(u & 0xffff0000u); }
DEV float sigm(float x) { return 1.0f / (1.0f + __expf(-x)); }

// Flag-aware loads: flags[0]=1 -> floats stored as bf16; flags[1]=1 -> ints are int64.
DEV float loadF(const void* p, int j, int isb) {
  return isb ? bf2f(((const ushort_t*)p)[j]) : ((const float*)p)[j];
}
DEV int loadI(const void* p, long long j, int is64) {
  return is64 ? (int)(((const long long*)p)[j]) : ((const int*)p)[j];
}

// ---------------------------------------------------------------------------
// Weight prep + dtype detection + workspace zeroing + tc2 B-fragment packing.
// W layout (float offsets):
//  tc1: Pw 0(48) Pb 48 Qw 64 Qb 112 Rw 128 Rb 176
//  tc2: Pw 192(768) Pb 960 Qw 976 Qb 1744 Rw 1760 Rb 2528
//  cheb: W0 2544(256) W1 2800(256) b 3056(16);  lin: W 3072(32) b 3104(2)
// Bf: tc2 weights as mfma_16x16x32_bf16 B-fragments, kappa = kk*16 + c
// (K=48 zero-padded to 64): Bf[((tau*2+s)*64 + lane)*8 + j] =
//   W_tau[kappa = s*32 + (lane>>4)*8 + j][n = lane&15],  0 for kappa >= 48.
// ---------------------------------------------------------------------------
__global__ void k_wprep(const void* ew, const void* ei,
                        const void* t1Pw, const void* t1Pb,
                        const void* t1Qw, const void* t1Qb,
                        const void* t1Rw, const void* t1Rb,
                        const void* t2Pw, const void* t2Pb,
                        const void* t2Qw, const void* t2Qb,
                        const void* t2Rw, const void* t2Rb,
                        const void* chw, const void* chb,
                        const void* lw, const void* lb,
                        int* flags, float* W, ushort_t* Bf, uint_t* zero_base) {
  int gid = blockIdx.x * 256 + threadIdx.x;
  if (gid < 9 * NP) zero_base[gid] = 0u;
  if (blockIdx.x != 0) return;

  __shared__ int sflags[2];
  int tid = threadIdx.x;
  if (tid < 64) {
    int lane = tid;
    const ushort_t* u = (const ushort_t*)ew;
    int cnt = 0;
    for (int j = lane; j < 512; j += 64) cnt += (u[j] < 0x3F80u) ? 1 : 0;
#pragma unroll
    for (int d = 32; d; d >>= 1) cnt += __shfl_xor(cnt, d, 64);
    const int* e32 = (const int*)ei;
    int even_nz = 0, odd_nz = 0;
    for (int j = 2 * lane; j < 256; j += 128) {
      even_nz |= (e32[j] != 0);
      odd_nz |= (e32[j + 1] != 0);
    }
    unsigned long long be = __ballot(even_nz), bo = __ballot(odd_nz);
    if (lane == 0) {
      int f0 = (cnt >= 450) ? 1 : 0;
      int f1 = (bo == 0ull && be != 0ull) ? 1 : 0;
      sflags[0] = f0; sflags[1] = f1;
      flags[0] = f0; flags[1] = f1;
    }
  }
  __syncthreads();
  int isb = sflags[0];
#define CVT(src, off, n) for (int j = tid; j < (n); j += 256) W[(off) + j] = loadF(src, j, isb);
  CVT(t1Pw, 0, 48)   CVT(t1Pb, 48, 16)
  CVT(t1Qw, 64, 48)  CVT(t1Qb, 112, 16)
  CVT(t1Rw, 128, 48) CVT(t1Rb, 176, 16)
  CVT(t2Pw, 192, 768)  CVT(t2Pb, 960, 16)
  CVT(t2Qw, 976, 768)  CVT(t2Qb, 1744, 16)
  CVT(t2Rw, 1760, 768) CVT(t2Rb, 2528, 16)
  CVT(chw, 2544, 512)  CVT(chb, 3056, 16)
  CVT(lw, 3072, 32)    CVT(lb, 3104, 2)
#undef CVT
  // Pack tc2 weights into B-fragments (reads inputs directly; no W dependency).
  for (int i = tid; i < 3072; i += 256) {
    int j = i & 7, lane = (i >> 3) & 63, s = (i >> 9) & 1, tau = i >> 10;
    int kap = s * 32 + ((lane >> 4) << 3) + j;
    int nsub = lane & 15;
    ushort_t v = 0;
    if (kap < 48) {
      int kk = kap >> 4, c = kap & 15;
      const void* src = (tau == 0) ? t2Pw : (tau == 1) ? t2Qw : t2Rw;
      v = f2bf(loadF(src, kk * 256 + c * 16 + nsub, isb));
    }
    Bf[i] = v;
  }
}

// ---------------------------------------------------------------------------
// Fused tc1 + degree accumulation + bucket scatter (single edge pass).
// R13-proven shape: thread per (b,t,n), 1M light threads, direct 32 B stores
// (R14 showed LDS-staged full-line writes buy nothing: WRITE is dominated by
// per-atomic writeback, invariant to store pattern). Packed 4 B ecv entries.
// ---------------------------------------------------------------------------
__global__ __launch_bounds__(256) void k_pre(const void* __restrict__ x,
                                             const void* __restrict__ ei,
                                             const void* __restrict__ ew,
                                             const float* __restrict__ W,
                                             const int* __restrict__ flags,
                                             ushort_t* __restrict__ xfh,
                                             float* __restrict__ deg8,
                                             int* __restrict__ cnt,
                                             uint_t* __restrict__ ecv) {
  int id = blockIdx.x * 256 + threadIdx.x;
  int isb = flags[0];
  if (id < Ee) {
    int is64 = flags[1];
    int s = loadI(ei, id, is64), d = loadI(ei, (long long)Ee + id, is64);
    float w = loadF(ew, id, isb);
    atomicAdd(&deg8[(blockIdx.x & 7) * NP + s], w);
    int pos = atomicAdd(&cnt[d], 1);
    if (pos < CAP) ecv[d * CAP + pos] = ((uint_t)s << 16) | (uint_t)f2bf(w);
  }
  if (id < Bb * T1 * Nn) {
    int n = id % Nn;
    int bt = id / Nn;
    int t = bt % T1, b = bt / T1;
    float x0 = loadF(x, (b * Tt + t + 0) * Nn + n, isb);
    float x1 = loadF(x, (b * Tt + t + 1) * Nn + n, isb);
    float x2 = loadF(x, (b * Tt + t + 2) * Nn + n, isb);
    ushort_t g[16];
#pragma unroll
    for (int h = 0; h < 16; ++h) {
      float p = W[48 + h] + x0 * W[0 + h] + x1 * W[16 + h] + x2 * W[32 + h];
      float q = W[112 + h] + x0 * W[64 + h] + x1 * W[80 + h] + x2 * W[96 + h];
      float r = W[176 + h] + x0 * W[128 + h] + x1 * W[144 + h] + x2 * W[160 + h];
      g[h] = f2bf(fmaxf(fmaf(p, sigm(q), r), 0.0f));
    }
    uint_t u[8];
#pragma unroll
    for (int j = 0; j < 8; ++j) u[j] = (uint_t)g[2 * j] | ((uint_t)g[2 * j + 1] << 16);
    uint4* dst = (uint4*)(xfh + (size_t)n * F + t * 32 + b * 16);
    dst[0] = make_uint4(u[0], u[1], u[2], u[3]);
    dst[1] = make_uint4(u[4], u[5], u[6], u[7]);
  }
}

// ---------------------------------------------------------------------------
// Reduce the 8 degree copies -> dis = 1/sqrt(deg), in place into copy 0.
// ---------------------------------------------------------------------------
__global__ __launch_bounds__(256) void k_dis(float* __restrict__ deg8) {
  int i = blockIdx.x * 256 + threadIdx.x;
  if (i >= Nn) return;
  float v = 0.0f;
#pragma unroll
  for (int j = 0; j < 8; ++j) v += deg8[j * NP + i];
  deg8[i] = (v > 0.0f) ? (1.0f / sqrtf(fmaxf(v, 1e-12f))) : 0.0f;
}

// ---------------------------------------------------------------------------
// Fused SpMM gather + Cheb combine + relu.  One wave per dst node.
// Packed 4 B bucket entries; valv = bf16(w)*dis[src]; 4-edge unroll (proven).
// Epilogue scales by -dis[dst], cheb-combines via wave-private LDS, stores
// h2 bf16.
// ---------------------------------------------------------------------------
__global__ __launch_bounds__(256) void k_agg(const int* __restrict__ cnt,
                                             const uint_t* __restrict__ ecv,
                                             const float* __restrict__ dis,
                                             const uint2* __restrict__ xf2,
                                             const float* __restrict__ W,
                                             ushort_t* __restrict__ h2) {
  __shared__ float sh[4][640];  // per wave: [0..319]=agg, [320..639]=x
  int wid = threadIdx.x >> 6;
  int lane = threadIdx.x & 63;
  int gw = blockIdx.x * 4 + wid;
  int deg = min(cnt[gw], CAP);
  int l16 = 64 + (lane & 15);
  float a0 = 0.f, a1 = 0.f, a2 = 0.f, a3 = 0.f;
  float c0 = 0.f, c1 = 0.f, c2 = 0.f, c3 = 0.f;

#define ACC(v, p, q)                                                          \
  a0 = fmaf(v, blo(p.x), a0); a1 = fmaf(v, bhi(p.x), a1);                     \
  a2 = fmaf(v, blo(p.y), a2); a3 = fmaf(v, bhi(p.y), a3);                     \
  c0 = fmaf(v, blo(q.x), c0); c1 = fmaf(v, bhi(q.x), c1);                     \
  c2 = fmaf(v, blo(q.y), c2); c3 = fmaf(v, bhi(q.y), c3);

  int colv = 0; float valv = 0.0f;
  if (lane < deg) {
    uint_t t = ecv[gw * CAP + lane];
    int src = t >> 16;
    colv = src * 80;  // row offset in uint2 units
    valv = bf2f((ushort_t)(t & 0xffffu)) * dis[src];
  }
  int e = 0;
  for (; e + 4 <= deg; e += 4) {
    int r0 = __shfl(colv, e + 0), r1 = __shfl(colv, e + 1);
    int r2 = __shfl(colv, e + 2), r3 = __shfl(colv, e + 3);
    float v0 = __shfl(valv, e + 0), v1 = __shfl(valv, e + 1);
    float v2 = __shfl(valv, e + 2), v3 = __shfl(valv, e + 3);
    uint2 p0 = xf2[r0 + lane], q0 = xf2[r0 + l16];
    uint2 p1 = xf2[r1 + lane], q1 = xf2[r1 + l16];
    uint2 p2 = xf2[r2 + lane], q2 = xf2[r2 + l16];
    uint2 p3 = xf2[r3 + lane], q3 = xf2[r3 + l16];
    ACC(v0, p0, q0) ACC(v1, p1, q1) ACC(v2, p2, q2) ACC(v3, p3, q3)
  }
  for (; e < deg; ++e) {
    int r = __shfl(colv, e);
    float v = __shfl(valv, e);
    uint2 p = xf2[r + lane], q = xf2[r + l16];
    ACC(v, p, q)
  }
#undef ACC

  float nd = -dis[gw];  // wave-uniform
  float* sa = sh[wid];
  float* sx = sh[wid] + 320;
  const uint2* xrow = xf2 + (size_t)gw * 80;
  uint2 xp = xrow[lane], xq = xrow[l16];
  ((float4*)sa)[lane] = make_float4(a0 * nd, a1 * nd, a2 * nd, a3 * nd);
  ((float4*)sx)[lane] = make_float4(blo(xp.x), bhi(xp.x), blo(xp.y), bhi(xp.y));
  if (lane < 16) {
    ((float4*)sa)[64 + lane] = make_float4(c0 * nd, c1 * nd, c2 * nd, c3 * nd);
    ((float4*)sx)[64 + lane] = make_float4(blo(xq.x), bhi(xq.x), blo(xq.y), bhi(xq.y));
  }
  __builtin_amdgcn_wave_barrier();  // wave-private LDS: block compiler reordering only
  int h = lane & 15;
  float w0[16], w1[16];
#pragma unroll
  for (int c = 0; c < 16; ++c) {
    w0[c] = W[2544 + c * 16 + h];
    w1[c] = W[2800 + c * 16 + h];
  }
  float bias = W[3056 + h];
  ushort_t* orow = h2 + (size_t)gw * F;
#pragma unroll
  for (int j = 0; j < 5; ++j) {
    int base2 = (lane & 48) + 64 * j;
    float o2 = bias;
#pragma unroll
    for (int c = 0; c < 16; ++c)
      o2 = fmaf(sx[base2 + c], w0[c], fmaf(sa[base2 + c], w1[c], o2));
    orow[lane + 64 * j] = f2bf(fmaxf(o2, 0.0f));
  }
}

// ---------------------------------------------------------------------------
// tc2 GLU via MFMA + mean + linear head.  Wave handles 4 nodes; per node the
// 16 (b,t2) pairs are the M dim of a 16x48x48 GEMM done as 3 N-tiles (P,Q,R)
// x 2 K-steps (K=48 padded to 64) of mfma_f32_16x16x32_bf16.
// A-frag: lane m=lane&15 (=pair), k=quad*8+j -> 16 B contiguous h2 loads.
// C/D: col=lane&15 (=h), row=quad*4+reg (=pair); quads 0,1 are b=0 rows,
// quads 2,3 b=1 -> mean over t2 = 4-reg sum + shfl_xor(16); head = 16-lane
// shuffle dot. Grid = Nn/16 = 3125 exactly.
// ---------------------------------------------------------------------------
__global__ __launch_bounds__(256) void k_tc2h(const ushort_t* __restrict__ h2,
                                              const ushort_t* __restrict__ Bf,
                                              const float* __restrict__ W,
                                              float* __restrict__ out) {
  int tid = threadIdx.x;
  int wid = tid >> 6, lane = tid & 63;
  int quad = lane >> 4, hcol = lane & 15;
  short8 bfr[3][2];
#pragma unroll
  for (int tau = 0; tau < 3; ++tau)
#pragma unroll
    for (int s = 0; s < 2; ++s)
      bfr[tau][s] = *(const short8*)(Bf + (tau * 1024 + s * 512 + lane * 8));
  float pb = W[960 + hcol], qb = W[1744 + hcol], rb = W[2528 + hcol];
  float lw0 = W[3072 + 2 * hcol], lw1 = W[3073 + 2 * hcol];
  float ob0 = W[3104], ob1 = W[3105];
  int bm = hcol >> 3, t2m = hcol & 7;       // pair this lane loads (A rows)
  int kk0 = quad >> 1, off0 = (quad & 1) * 8;
#pragma unroll
  for (int nn = 0; nn < 4; ++nn) {
    int n = blockIdx.x * 16 + wid * 4 + nn;
    const ushort_t* row = h2 + (size_t)n * F;
    short8 a0 = *(const short8*)(row + (t2m + kk0) * 32 + bm * 16 + off0);
    short8 a1 = (short8)0;
    if (quad < 2) a1 = *(const short8*)(row + (t2m + 2) * 32 + bm * 16 + quad * 8);
    float4v accP = {0.f, 0.f, 0.f, 0.f};
    float4v accQ = {0.f, 0.f, 0.f, 0.f};
    float4v accR = {0.f, 0.f, 0.f, 0.f};
    accP = __builtin_amdgcn_mfma_f32_16x16x32_bf16(a0, bfr[0][0], accP, 0, 0, 0);
    accP = __builtin_amdgcn_mfma_f32_16x16x32_bf16(a1, bfr[0][1], accP, 0, 0, 0);
    accQ = __builtin_amdgcn_mfma_f32_16x16x32_bf16(a0, bfr[1][0], accQ, 0, 0, 0);
    accQ = __builtin_amdgcn_mfma_f32_16x16x32_bf16(a1, bfr[1][1], accQ, 0, 0, 0);
    accR = __builtin_amdgcn_mfma_f32_16x16x32_bf16(a0, bfr[2][0], accR, 0, 0, 0);
    accR = __builtin_amdgcn_mfma_f32_16x16x32_bf16(a1, bfr[2][1], accR, 0, 0, 0);
    float s0 = 0.0f;
#pragma unroll
    for (int r = 0; r < 4; ++r) {
      float P = accP[r] + pb, Q = accQ[r] + qb, R = accR[r] + rb;
      s0 += fmaxf(fmaf(P, sigm(Q), R), 0.0f);
    }
    s0 += __shfl_xor(s0, 16);   // quads {0,1}: b=0 over all 8 t2; {2,3}: b=1
    float mmean = s0 * 0.125f;
    float u0 = mmean * lw0, u1 = mmean * lw1;
#pragma unroll
    for (int d = 1; d < 16; d <<= 1) {
      u0 += __shfl_xor(u0, d);
      u1 += __shfl_xor(u1, d);
    }
    if ((lane & 31) == 0) {
      int b = lane >> 5;
      ((float2*)out)[(size_t)b * Nn + n] = make_float2(u0 + ob0, u1 + ob1);
    }
  }
}

// ---------------------------------------------------------------------------
extern "C" void kernel_launch(void* const* d_in, const int* in_sizes, int n_in,
                              void* d_out, int out_size, void* d_ws, size_t ws_size,
                              hipStream_t stream) {
  (void)in_sizes; (void)n_in; (void)out_size; (void)ws_size;
  const void* x = d_in[0];
  const void* ei = d_in[1];
  const void* ew = d_in[2];

  char* wsb = (char*)d_ws;
  size_t off = 0;
  auto alloc = [&](size_t bytes) -> void* {
    void* p = wsb + off;
    off = (off + bytes + 255) & ~(size_t)255;
    return p;
  };
  int* flags = (int*)alloc(256);
  float* W = (float*)alloc(4096 * 4);
  ushort_t* Bf = (ushort_t*)alloc(3072 * 2);             // tc2 B-fragments (bf16)
  float* deg8 = (float*)alloc((size_t)8 * NP * 4);       // copy0 becomes dis
  int* cnt = (int*)alloc((size_t)NP * 4);                // contiguous after deg8
  uint_t* ecv = (uint_t*)alloc((size_t)Nn * CAP * 4);    // packed (src<<16|bf16 w)
  ushort_t* xfh = (ushort_t*)alloc((size_t)Nn * F * 2);  // h1 bf16 (f = t*32+b*16+h)
  ushort_t* h2 = (ushort_t*)alloc((size_t)Nn * F * 2);   // cheb output bf16
  // total ~79 MB of d_ws

  int zblk = (9 * NP + 255) / 256;  // block 0 also does detection + weights + Bf
  k_wprep<<<zblk, 256, 0, stream>>>(
      ew, ei,
      d_in[3], d_in[4], d_in[5], d_in[6], d_in[7], d_in[8],
      d_in[9], d_in[10], d_in[11], d_in[12], d_in[13], d_in[14],
      d_in[15], d_in[16], d_in[17], d_in[18], flags, W, Bf, (uint_t*)deg8);

  k_pre<<<(Bb * T1 * Nn + 255) / 256, 256, 0, stream>>>(x, ei, ew, W, flags, xfh, deg8, cnt, ecv);
  k_dis<<<(Nn + 255) / 256, 256, 0, stream>>>(deg8);
  k_agg<<<Nn / 4, 256, 0, stream>>>(cnt, ecv, deg8, (const uint2*)xfh, W, h2);
  k_tc2h<<<Nn / 16, 256, 0, stream>>>(h2, Bf, W, (float*)d_out);
}